// Round 15
// baseline (254.307 us; speedup 1.0000x reference)
//
#include <hip/hip_runtime.h>

typedef __attribute__((ext_vector_type(8))) short bf16x8;
typedef __attribute__((ext_vector_type(4))) float f32x4;
typedef __attribute__((ext_vector_type(2))) float f32x2;
typedef __attribute__((ext_vector_type(2))) uint u32x2;

static inline size_t align256(size_t x) { return (x + 255) & ~size_t(255); }

__device__ inline ushort f2bf(float f) {
  uint u = __float_as_uint(f);
  return (ushort)((u + 0x7FFFu + ((u >> 16) & 1u)) >> 16);  // RNE
}
__device__ inline float bf2f(ushort h) { return __uint_as_float(((uint)h) << 16); }

// ---- fp8 e4m3 codec (HW cvt if available; self-consistent fallback) ----

__device__ inline uint fp8x4_enc(float a0, float a1, float a2, float a3) {
#if __has_builtin(__builtin_amdgcn_cvt_pk_fp8_f32)
  int v = 0;
  v = __builtin_amdgcn_cvt_pk_fp8_f32(a0, a1, v, false);
  v = __builtin_amdgcn_cvt_pk_fp8_f32(a2, a3, v, true);
  return (uint)v;
#else
  float a[4] = {a0, a1, a2, a3};
  uint r = 0;
#pragma unroll
  for (int k = 0; k < 4; ++k) {
    uint u = __float_as_uint(a[k]);
    uint s = (u >> 24) & 0x80u;
    uint au = u & 0x7FFFFFFFu;
    uint b;
    if (au < 0x3C800000u) {
      b = s;
    } else {
      uint rr = au + 0x7FFFFu + ((au >> 20) & 1u);
      uint e = (rr >> 23) - 120u;
      uint m = (rr >> 20) & 7u;
      b = s | (e << 3) | m;
    }
    r |= b << (8 * k);
  }
  return r;
#endif
}

__device__ inline f32x4 fp8x4_dec(uint u) {
  f32x4 r;
#if __has_builtin(__builtin_amdgcn_cvt_pk_f32_fp8)
  auto lo = __builtin_amdgcn_cvt_pk_f32_fp8((int)u, false);
  auto hi = __builtin_amdgcn_cvt_pk_f32_fp8((int)u, true);
  r[0] = lo[0]; r[1] = lo[1]; r[2] = hi[0]; r[3] = hi[1];
#else
#pragma unroll
  for (int k = 0; k < 4; ++k) {
    uint b = (u >> (8 * k)) & 0xFFu;
    uint f = ((b & 0x80u) << 24) | (((b & 0x7Fu) + (120u << 3)) << 20);
    r[k] = (b & 0x7Fu) ? __uint_as_float(f) : 0.f;
  }
#endif
  return r;
}

// edge record: u = (col<<15) | (bf16(w) sans sign, 15 bits)
__device__ inline float ew_dec(uint u) { return __uint_as_float((u & 0x7FFFu) << 16); }

#define BW_SHIFT 7            // 128 nodes per bucket
#define NBUCK_MAX 1024
#define NCHUNK 256
#define PREP_BLOCKS 96        // 3*16384/512

// ---- A+B merged: chunk hist (LDS-resident) + W prep + in-kernel grid
// barrier (ticket -> winner scans buckets -> flag release) + binned scatter.
// All 352 blocks are co-resident (2816 waves << 8192 capacity), so the
// spin-wait cannot deadlock.

__global__ __launch_bounds__(512) void build_ab_kernel(
    const int* __restrict__ row, const int* __restrict__ col,
    const float* __restrict__ w, int* __restrict__ bcnt, int E, int chunk,
    const float* __restrict__ W0, const float* __restrict__ W1,
    const float* __restrict__ W2, ushort* __restrict__ Wt,
    int* __restrict__ done, int* __restrict__ flag,
    int* __restrict__ boff, int* __restrict__ gcur,
    int* __restrict__ offp, int2* __restrict__ es_tmp, int n) {
  __shared__ int h[NBUCK_MAX];       // chunk hist (hist blocks), kept live
  __shared__ int lbase[NBUCK_MAX];   // scan scratch (winner) / run bases
  int bid = blockIdx.x;
  int t = threadIdx.x;
  bool is_hist = (bid < NCHUNK);
  int c0 = bid * chunk, c1 = min(c0 + chunk, E);
  if (is_hist) {
    for (int i = t; i < NBUCK_MAX; i += 512) h[i] = 0;
    __syncthreads();
    for (int i = c0 + t; i < c1; i += 512)
      atomicAdd(&h[row[i] >> BW_SHIFT], 1);
    __syncthreads();
    for (int i = t; i < NBUCK_MAX; i += 512)
      if (h[i]) atomicAdd(&bcnt[i], h[i]);
  } else {
    int i = (bid - NCHUNK) * 512 + t;  // < 3*16384
    int mat = i >> 14, r = i & 16383;
    int k = r >> 7, c = r & 127;
    const float* W = (mat == 0) ? W0 : (mat == 1) ? W1 : W2;
    Wt[mat * 16384 + c * 128 + k] = f2bf(W[k * 128 + c]);
  }
  __shared__ int ticket;
  __syncthreads();
  if (t == 0) {
    __threadfence();
    ticket = atomicAdd(done, 1);
  }
  __syncthreads();
  if (ticket == (int)gridDim.x - 1) {
    // winner: 1024-bin exclusive scan (scratch = lbase[0..511])
    __threadfence();
    int v0 = bcnt[2 * t], v1 = bcnt[2 * t + 1];
    int pair = v0 + v1;
    lbase[t] = pair;
    __syncthreads();
    for (int o = 1; o < 512; o <<= 1) {
      int a = (t >= o) ? lbase[t - o] : 0;
      __syncthreads();
      lbase[t] += a;
      __syncthreads();
    }
    int excl = lbase[t] - pair;
    boff[2 * t] = excl;          gcur[2 * t] = excl;
    boff[2 * t + 1] = excl + v0; gcur[2 * t + 1] = excl + v0;
    if (t == 511) boff[NBUCK_MAX] = E;
    if (t == 0) {
      offp[n] = E;
      __threadfence();
      __hip_atomic_store(flag, 1, __ATOMIC_RELEASE, __HIP_MEMORY_SCOPE_AGENT);
    }
    __syncthreads();
  }
  if (!is_hist) return;  // prep blocks done
  // wait for bucket offsets
  if (t == 0) {
    while (__hip_atomic_load(flag, __ATOMIC_ACQUIRE, __HIP_MEMORY_SCOPE_AGENT) == 0)
      __builtin_amdgcn_s_sleep(8);
  }
  __syncthreads();
  // reserve per-bucket runs from LDS-resident hist, then scatter
  for (int i = t; i < NBUCK_MAX; i += 512) {
    int c = h[i];
    lbase[i] = c ? atomicAdd(&gcur[i], c) : 0;
    h[i] = 0;  // becomes local cursor
  }
  __syncthreads();
  for (int i = c0 + t; i < c1; i += 512) {
    int r = row[i];
    int b = r >> BW_SHIFT;
    int pos = lbase[b] + atomicAdd(&h[b], 1);
    es_tmp[pos] = make_int2(((r & 127) << 17) | col[i], __float_as_int(w[i]));
  }
}

// ---- C+G fused: per-bucket node sort (4-B records) + 3x MFMA GEMM ----

__global__ __launch_bounds__(256) void sort_gemm_kernel(
    const int2* __restrict__ es_tmp, const int* __restrict__ boff,
    uint* __restrict__ es, int* __restrict__ offp, int ng,
    const float* __restrict__ x, const ushort* __restrict__ Wt,
    const float* __restrict__ b0, const float* __restrict__ b1,
    const float* __restrict__ b2,
    float* __restrict__ out0, unsigned char* __restrict__ y12, int n) {
  int t = threadIdx.x;
  if ((int)blockIdx.x >= ng) {
    // ---------- bucket_sort role ----------
    __shared__ int lh[128];
    __shared__ int lex[128];
    int b = (int)blockIdx.x - ng;
    int base = boff[b], cnt = boff[b + 1] - base;
    if (t < 128) lh[t] = 0;
    __syncthreads();
    for (int i = t; i < cnt; i += 256)
      atomicAdd(&lh[(es_tmp[base + i].x >> 17) & 127], 1);
    __syncthreads();
    if (t < 128) lex[t] = lh[t];
    __syncthreads();
    for (int o = 1; o < 128; o <<= 1) {
      int a = (t >= o && t < 128) ? lex[t - o] : 0;
      __syncthreads();
      if (t < 128) lex[t] += a;
      __syncthreads();
    }
    if (t < 128) {
      int v = lh[t];
      int excl = lex[t] - v;
      int node = (b << BW_SHIFT) + t;
      if (node < n) offp[node] = base + excl;
      lh[t] = excl;  // cursor
    }
    __syncthreads();
    for (int i = t; i < cnt; i += 256) {
      int2 ed = es_tmp[base + i];
      int nl = (ed.x >> 17) & 127;
      int pos = base + atomicAdd(&lh[nl], 1);
      uint wb = (uint)f2bf(__int_as_float(ed.y)) & 0x7FFFu;
      es[pos] = ((uint)(ed.x & 0x1FFFF) << 15) | wb;
    }
    return;
  }
  // ---------- gemm role ----------
  int w = t >> 6;
  int l = t & 63;
  int lr = l & 15;
  int lg = l >> 4;
  int rows0 = (int)blockIdx.x * 256 + w * 64;

  bf16x8 xf[4][4];
#pragma unroll
  for (int rt = 0; rt < 4; ++rt) {
    int row = rows0 + rt * 16 + lr;
    bool ok = row < n;
    const float* base = x + (size_t)row * 128;
#pragma unroll
    for (int kc = 0; kc < 4; ++kc) {
      float4 a = ok ? *(const float4*)(base + kc * 32 + lg * 8) : make_float4(0, 0, 0, 0);
      float4 c = ok ? *(const float4*)(base + kc * 32 + lg * 8 + 4) : make_float4(0, 0, 0, 0);
      bf16x8 f;
      f[0] = (short)f2bf(a.x); f[1] = (short)f2bf(a.y);
      f[2] = (short)f2bf(a.z); f[3] = (short)f2bf(a.w);
      f[4] = (short)f2bf(c.x); f[5] = (short)f2bf(c.y);
      f[6] = (short)f2bf(c.z); f[7] = (short)f2bf(c.w);
      xf[rt][kc] = f;
    }
  }

  for (int mat = 0; mat < 3; ++mat) {
    const ushort* Wm = Wt + mat * 16384;
    const float* bias = (mat == 0) ? b0 : (mat == 1) ? b1 : b2;
#pragma unroll 1
    for (int ct = 0; ct < 8; ++ct) {
      bf16x8 wf[4];
#pragma unroll
      for (int kc = 0; kc < 4; ++kc)
        wf[kc] = *(const bf16x8*)(Wm + (ct * 16 + lr) * 128 + kc * 32 + lg * 8);
      float4 bb = *(const float4*)(bias + ct * 16 + lg * 4);
      f32x4 acc[4];
#pragma unroll
      for (int rt = 0; rt < 4; ++rt) {
        acc[rt][0] = bb.x; acc[rt][1] = bb.y; acc[rt][2] = bb.z; acc[rt][3] = bb.w;
      }
#pragma unroll
      for (int kc = 0; kc < 4; ++kc)
#pragma unroll
        for (int rt = 0; rt < 4; ++rt)
          acc[rt] = __builtin_amdgcn_mfma_f32_16x16x32_bf16(wf[kc], xf[rt][kc], acc[rt], 0, 0, 0);
#pragma unroll
      for (int rt = 0; rt < 4; ++rt) {
        int row = rows0 + rt * 16 + lr;
        if (row >= n) continue;
        int col = ct * 16 + lg * 4;
        if (mat == 0) {
          __builtin_nontemporal_store(acc[rt], (f32x4*)(out0 + (size_t)row * 384 + col));
        } else {
          uint v8 = fp8x4_enc(acc[rt][0], acc[rt][1], acc[rt][2], acc[rt][3]);
          unsigned char* Y = y12 + (size_t)row * 256 + ((mat == 2) ? 128 : 0) + col;
          *(uint*)Y = v8;
        }
      }
    }
  }
}

// ---- D: SpMM dual (fp8 gather, full wave per node, 4 B/lane) ----

__global__ __launch_bounds__(256) void spmm_dual_kernel(
    const unsigned char* __restrict__ y12,
    float* __restrict__ o1,        // d_out + 128, stride 384
    ushort* __restrict__ z2,       // bf16, stride 128 (re-read -> cached)
    const int* __restrict__ off, const uint* __restrict__ es, int n) {
  int node = blockIdx.x * 4 + (threadIdx.x >> 6);
  if (node >= n) return;
  int l = threadIdx.x & 63;
  int s = __builtin_amdgcn_readfirstlane(off[node]);
  int e = __builtin_amdgcn_readfirstlane(off[node + 1]);
  float a0 = 0.f, a1 = 0.f, a2 = 0.f, a3 = 0.f;
  int i = s;
  for (; i + 8 <= e; i += 8) {
    uint u[8];
    float w[8];
#pragma unroll
    for (int j = 0; j < 8; ++j) {
      uint ed = es[i + j];
      w[j] = ew_dec(ed);
      u[j] = *(const uint*)(y12 + (size_t)(ed >> 15) * 256 + l * 4);
    }
#pragma unroll
    for (int j = 0; j < 8; ++j) {
      f32x4 p = fp8x4_dec(u[j]);
      a0 += w[j] * p[0]; a1 += w[j] * p[1];
      a2 += w[j] * p[2]; a3 += w[j] * p[3];
    }
  }
  for (; i < e; ++i) {
    uint ed = es[i];
    float w = ew_dec(ed);
    f32x4 p = fp8x4_dec(*(const uint*)(y12 + (size_t)(ed >> 15) * 256 + l * 4));
    a0 += w * p[0]; a1 += w * p[1]; a2 += w * p[2]; a3 += w * p[3];
  }
  if (l < 32) {
    f32x4 v; v[0] = a0; v[1] = a1; v[2] = a2; v[3] = a3;
    __builtin_nontemporal_store(v, (f32x4*)(o1 + (size_t)node * 384 + l * 4));
  } else {
    u32x2 z;
    z.x = (uint)f2bf(a0) | ((uint)f2bf(a1) << 16);
    z.y = (uint)f2bf(a2) | ((uint)f2bf(a3) << 16);
    *(u32x2*)(z2 + (size_t)node * 128 + (l - 32) * 4) = z;
  }
}

// ---- E: SpMM single (bf16 gather, full wave per node, 4 B/lane = 2 ch) ----

__global__ __launch_bounds__(256) void spmm_single_kernel(
    const ushort* __restrict__ z2,
    float* __restrict__ o2,        // d_out + 256, stride 384
    const int* __restrict__ off, const uint* __restrict__ es, int n) {
  int node = blockIdx.x * 4 + (threadIdx.x >> 6);
  if (node >= n) return;
  int l = threadIdx.x & 63;
  int s = __builtin_amdgcn_readfirstlane(off[node]);
  int e = __builtin_amdgcn_readfirstlane(off[node + 1]);
  float a0 = 0.f, a1 = 0.f;
  int i = s;
  for (; i + 8 <= e; i += 8) {
    uint u[8];
    float w[8];
#pragma unroll
    for (int j = 0; j < 8; ++j) {
      uint ed = es[i + j];
      w[j] = ew_dec(ed);
      u[j] = *(const uint*)(z2 + (size_t)(ed >> 15) * 128 + l * 2);
    }
#pragma unroll
    for (int j = 0; j < 8; ++j) {
      a0 += w[j] * bf2f((ushort)u[j]); a1 += w[j] * bf2f((ushort)(u[j] >> 16));
    }
  }
  for (; i < e; ++i) {
    uint ed = es[i];
    float w = ew_dec(ed);
    uint u = *(const uint*)(z2 + (size_t)(ed >> 15) * 128 + l * 2);
    a0 += w * bf2f((ushort)u); a1 += w * bf2f((ushort)(u >> 16));
  }
  f32x2 v; v.x = a0; v.y = a1;
  __builtin_nontemporal_store(v, (f32x2*)(o2 + (size_t)node * 384 + l * 2));
}

// ---------------- launch ----------------

extern "C" void kernel_launch(void* const* d_in, const int* in_sizes, int n_in,
                              void* d_out, int out_size, void* d_ws, size_t ws_size,
                              hipStream_t stream) {
  const float* x   = (const float*)d_in[0];
  const int*   row = (const int*)d_in[1];
  const int*   col = (const int*)d_in[2];
  const float* ew  = (const float*)d_in[3];
  const float* W0  = (const float*)d_in[4];
  const float* b0  = (const float*)d_in[5];
  const float* W1  = (const float*)d_in[6];
  const float* b1  = (const float*)d_in[7];
  const float* W2  = (const float*)d_in[8];
  const float* b2  = (const float*)d_in[9];
  float* out = (float*)d_out;

  int n = in_sizes[0] / 128;
  int E = in_sizes[1];

  char* p = (char*)d_ws;
  size_t o = 0;
  unsigned char* y12 = (unsigned char*)(p + o); o = align256(o + (size_t)n * 256);
  ushort* z2  = (ushort*)(p + o); o = align256(o + (size_t)n * 128 * 2);
  ushort* Wt  = (ushort*)(p + o); o = align256(o + (size_t)3 * 16384 * 2);
  int* bcnt   = (int*)(p + o);    o = align256(o + (size_t)(NBUCK_MAX + 2) * 4);
  int* done   = bcnt + NBUCK_MAX;      // zeroed with bcnt
  int* flag   = bcnt + NBUCK_MAX + 1;  // zeroed with bcnt
  int* boff   = (int*)(p + o);    o = align256(o + (size_t)(NBUCK_MAX + 1) * 4);
  int* gcur   = (int*)(p + o);    o = align256(o + (size_t)NBUCK_MAX * 4);
  int* offp   = (int*)(p + o);    o = align256(o + ((size_t)n + 1) * 4);
  int2* es_t  = (int2*)(p + o);   o = align256(o + (size_t)E * 8);
  uint* es    = (uint*)(p + o);   o = align256(o + (size_t)E * 4);
  (void)ws_size; (void)n_in; (void)out_size;

  int nbuck = (n + 127) >> 7;
  int ng = (n + 255) / 256;
  int chunk = (E + NCHUNK - 1) / NCHUNK;

  hipMemsetAsync(bcnt, 0, (size_t)(NBUCK_MAX + 2) * 4, stream);

  // A+B: chunk hist + W prep + grid barrier + binned scatter (one dispatch)
  build_ab_kernel<<<NCHUNK + PREP_BLOCKS, 512, 0, stream>>>(
      row, col, ew, bcnt, E, chunk, W0, W1, W2, Wt, done, flag,
      boff, gcur, offp, es_t, n);

  // C+G: per-bucket node sort (4-B records) + fused 3x GEMM
  sort_gemm_kernel<<<ng + nbuck, 256, 0, stream>>>(
      es_t, boff, es, offp, ng,
      x, Wt, b0, b1, b2, out, y12, n);

  // D: x1 -> out[:,128:256] (NT), z2 (bf16, cached) -> ws
  spmm_dual_kernel<<<(n + 3) / 4, 256, 0, stream>>>(y12, out + 128, z2,
                                                    offp, es, n);
  // E: x2 = A*z2 -> out[:,256:384] (NT)
  spmm_single_kernel<<<(n + 3) / 4, 256, 0, stream>>>(z2, out + 256,
                                                      offp, es, n);
}

// Round 16
// 226.075 us; speedup vs baseline: 1.1249x; 1.1249x over previous
//
#include <hip/hip_runtime.h>

typedef __attribute__((ext_vector_type(8))) short bf16x8;
typedef __attribute__((ext_vector_type(4))) float f32x4;
typedef __attribute__((ext_vector_type(2))) float f32x2;
typedef __attribute__((ext_vector_type(2))) uint u32x2;

static inline size_t align256(size_t x) { return (x + 255) & ~size_t(255); }

__device__ inline ushort f2bf(float f) {
  uint u = __float_as_uint(f);
  return (ushort)((u + 0x7FFFu + ((u >> 16) & 1u)) >> 16);  // RNE
}
__device__ inline float bf2f(ushort h) { return __uint_as_float(((uint)h) << 16); }

// ---- fp8 e4m3 codec (HW cvt if available; self-consistent fallback) ----

__device__ inline uint fp8x4_enc(float a0, float a1, float a2, float a3) {
#if __has_builtin(__builtin_amdgcn_cvt_pk_fp8_f32)
  int v = 0;
  v = __builtin_amdgcn_cvt_pk_fp8_f32(a0, a1, v, false);
  v = __builtin_amdgcn_cvt_pk_fp8_f32(a2, a3, v, true);
  return (uint)v;
#else
  float a[4] = {a0, a1, a2, a3};
  uint r = 0;
#pragma unroll
  for (int k = 0; k < 4; ++k) {
    uint u = __float_as_uint(a[k]);
    uint s = (u >> 24) & 0x80u;
    uint au = u & 0x7FFFFFFFu;
    uint b;
    if (au < 0x3C800000u) {
      b = s;
    } else {
      uint rr = au + 0x7FFFFu + ((au >> 20) & 1u);
      uint e = (rr >> 23) - 120u;
      uint m = (rr >> 20) & 7u;
      b = s | (e << 3) | m;
    }
    r |= b << (8 * k);
  }
  return r;
#endif
}

__device__ inline f32x4 fp8x4_dec(uint u) {
  f32x4 r;
#if __has_builtin(__builtin_amdgcn_cvt_pk_f32_fp8)
  auto lo = __builtin_amdgcn_cvt_pk_f32_fp8((int)u, false);
  auto hi = __builtin_amdgcn_cvt_pk_f32_fp8((int)u, true);
  r[0] = lo[0]; r[1] = lo[1]; r[2] = hi[0]; r[3] = hi[1];
#else
#pragma unroll
  for (int k = 0; k < 4; ++k) {
    uint b = (u >> (8 * k)) & 0xFFu;
    uint f = ((b & 0x80u) << 24) | (((b & 0x7Fu) + (120u << 3)) << 20);
    r[k] = (b & 0x7Fu) ? __uint_as_float(f) : 0.f;
  }
#endif
  return r;
}

// edge record: u = (col<<15) | (bf16(w) sans sign, 15 bits)
__device__ inline float ew_dec(uint u) { return __uint_as_float((u & 0x7FFFu) << 16); }

#define BW_SHIFT 7            // 128 nodes per bucket
#define NBUCK_MAX 1024
#define NCHUNK 256
#define PREP_BLOCKS 96        // 3*16384/512

// ---- A: chunk-aligned bucket hist (persisted) + W prep + tail bucket-scan ----

__global__ __launch_bounds__(512) void build_a_kernel(
    const int* __restrict__ row, int* __restrict__ bcnt,
    int* __restrict__ chunk_hist, int E, int chunk,
    const float* __restrict__ W0, const float* __restrict__ W1,
    const float* __restrict__ W2, ushort* __restrict__ Wt,
    int* __restrict__ done, int* __restrict__ boff, int* __restrict__ gcur,
    int* __restrict__ offp, int n) {
  __shared__ int h[NBUCK_MAX];
  int bid = blockIdx.x;
  int t = threadIdx.x;
  if (bid < NCHUNK) {
    for (int i = t; i < NBUCK_MAX; i += 512) h[i] = 0;
    __syncthreads();
    int c0 = bid * chunk, c1 = min(c0 + chunk, E);
    for (int i = c0 + t; i < c1; i += 512)
      atomicAdd(&h[row[i] >> BW_SHIFT], 1);
    __syncthreads();
    for (int i = t; i < NBUCK_MAX; i += 512) {
      int c = h[i];
      chunk_hist[bid * NBUCK_MAX + i] = c;
      if (c) atomicAdd(&bcnt[i], c);
    }
  } else {
    int i = (bid - NCHUNK) * 512 + t;  // < 3*16384
    int mat = i >> 14, r = i & 16383;
    int k = r >> 7, c = r & 127;
    const float* W = (mat == 0) ? W0 : (mat == 1) ? W1 : W2;
    Wt[mat * 16384 + c * 128 + k] = f2bf(W[k * 128 + c]);
  }
  __shared__ int ticket;
  __syncthreads();
  if (t == 0) {
    __threadfence();
    ticket = atomicAdd(done, 1);
  }
  __syncthreads();
  if (ticket == (int)gridDim.x - 1) {
    __threadfence();
    int v0 = bcnt[2 * t], v1 = bcnt[2 * t + 1];
    int pair = v0 + v1;
    h[t] = pair;
    __syncthreads();
    for (int o = 1; o < 512; o <<= 1) {
      int a = (t >= o) ? h[t - o] : 0;
      __syncthreads();
      h[t] += a;
      __syncthreads();
    }
    int excl = h[t] - pair;
    boff[2 * t] = excl;          gcur[2 * t] = excl;
    boff[2 * t + 1] = excl + v0; gcur[2 * t + 1] = excl + v0;
    if (t == 511) boff[NBUCK_MAX] = E;
    if (t == 0) offp[n] = E;
  }
}

// ---- B: binned scatter (reuses chunk_hist; no counting pass) ----

__global__ __launch_bounds__(512) void bin_scatter(
    const int* __restrict__ row, const int* __restrict__ col,
    const float* __restrict__ w, int* __restrict__ gcur,
    const int* __restrict__ chunk_hist, int2* __restrict__ es_tmp,
    int E, int chunk) {
  __shared__ int lbase[NBUCK_MAX];
  __shared__ int lh[NBUCK_MAX];
  int bid = blockIdx.x;
  int t = threadIdx.x;
  for (int i = t; i < NBUCK_MAX; i += 512) {
    int c = chunk_hist[bid * NBUCK_MAX + i];
    lbase[i] = c ? atomicAdd(&gcur[i], c) : 0;
    lh[i] = 0;
  }
  __syncthreads();
  int c0 = bid * chunk, c1 = min(c0 + chunk, E);
  for (int i = c0 + t; i < c1; i += 512) {
    int r = row[i];
    int b = r >> BW_SHIFT;
    int pos = lbase[b] + atomicAdd(&lh[b], 1);
    es_tmp[pos] = make_int2(((r & 127) << 17) | col[i], __float_as_int(w[i]));
  }
}

// ---- C+G fused: per-bucket node sort (4-B records) + 3x MFMA GEMM ----

__global__ __launch_bounds__(256) void sort_gemm_kernel(
    const int2* __restrict__ es_tmp, const int* __restrict__ boff,
    uint* __restrict__ es, int* __restrict__ offp, int ng,
    const float* __restrict__ x, const ushort* __restrict__ Wt,
    const float* __restrict__ b0, const float* __restrict__ b1,
    const float* __restrict__ b2,
    float* __restrict__ out0, unsigned char* __restrict__ y12, int n) {
  int t = threadIdx.x;
  if ((int)blockIdx.x >= ng) {
    // ---------- bucket_sort role ----------
    __shared__ int lh[128];
    __shared__ int lex[128];
    int b = (int)blockIdx.x - ng;
    int base = boff[b], cnt = boff[b + 1] - base;
    if (t < 128) lh[t] = 0;
    __syncthreads();
    for (int i = t; i < cnt; i += 256)
      atomicAdd(&lh[(es_tmp[base + i].x >> 17) & 127], 1);
    __syncthreads();
    if (t < 128) lex[t] = lh[t];
    __syncthreads();
    for (int o = 1; o < 128; o <<= 1) {
      int a = (t >= o && t < 128) ? lex[t - o] : 0;
      __syncthreads();
      if (t < 128) lex[t] += a;
      __syncthreads();
    }
    if (t < 128) {
      int v = lh[t];
      int excl = lex[t] - v;
      int node = (b << BW_SHIFT) + t;
      if (node < n) offp[node] = base + excl;
      lh[t] = excl;  // cursor
    }
    __syncthreads();
    for (int i = t; i < cnt; i += 256) {
      int2 ed = es_tmp[base + i];
      int nl = (ed.x >> 17) & 127;
      int pos = base + atomicAdd(&lh[nl], 1);
      uint wb = (uint)f2bf(__int_as_float(ed.y)) & 0x7FFFu;
      es[pos] = ((uint)(ed.x & 0x1FFFF) << 15) | wb;
    }
    return;
  }
  // ---------- gemm role ----------
  int w = t >> 6;
  int l = t & 63;
  int lr = l & 15;
  int lg = l >> 4;
  int rows0 = (int)blockIdx.x * 256 + w * 64;

  bf16x8 xf[4][4];
#pragma unroll
  for (int rt = 0; rt < 4; ++rt) {
    int row = rows0 + rt * 16 + lr;
    bool ok = row < n;
    const float* base = x + (size_t)row * 128;
#pragma unroll
    for (int kc = 0; kc < 4; ++kc) {
      float4 a = ok ? *(const float4*)(base + kc * 32 + lg * 8) : make_float4(0, 0, 0, 0);
      float4 c = ok ? *(const float4*)(base + kc * 32 + lg * 8 + 4) : make_float4(0, 0, 0, 0);
      bf16x8 f;
      f[0] = (short)f2bf(a.x); f[1] = (short)f2bf(a.y);
      f[2] = (short)f2bf(a.z); f[3] = (short)f2bf(a.w);
      f[4] = (short)f2bf(c.x); f[5] = (short)f2bf(c.y);
      f[6] = (short)f2bf(c.z); f[7] = (short)f2bf(c.w);
      xf[rt][kc] = f;
    }
  }

  for (int mat = 0; mat < 3; ++mat) {
    const ushort* Wm = Wt + mat * 16384;
    const float* bias = (mat == 0) ? b0 : (mat == 1) ? b1 : b2;
#pragma unroll 1
    for (int ct = 0; ct < 8; ++ct) {
      bf16x8 wf[4];
#pragma unroll
      for (int kc = 0; kc < 4; ++kc)
        wf[kc] = *(const bf16x8*)(Wm + (ct * 16 + lr) * 128 + kc * 32 + lg * 8);
      float4 bb = *(const float4*)(bias + ct * 16 + lg * 4);
      f32x4 acc[4];
#pragma unroll
      for (int rt = 0; rt < 4; ++rt) {
        acc[rt][0] = bb.x; acc[rt][1] = bb.y; acc[rt][2] = bb.z; acc[rt][3] = bb.w;
      }
#pragma unroll
      for (int kc = 0; kc < 4; ++kc)
#pragma unroll
        for (int rt = 0; rt < 4; ++rt)
          acc[rt] = __builtin_amdgcn_mfma_f32_16x16x32_bf16(wf[kc], xf[rt][kc], acc[rt], 0, 0, 0);
#pragma unroll
      for (int rt = 0; rt < 4; ++rt) {
        int row = rows0 + rt * 16 + lr;
        if (row >= n) continue;
        int col = ct * 16 + lg * 4;
        if (mat == 0) {
          __builtin_nontemporal_store(acc[rt], (f32x4*)(out0 + (size_t)row * 384 + col));
        } else {
          uint v8 = fp8x4_enc(acc[rt][0], acc[rt][1], acc[rt][2], acc[rt][3]);
          unsigned char* Y = y12 + (size_t)row * 256 + ((mat == 2) ? 128 : 0) + col;
          *(uint*)Y = v8;
        }
      }
    }
  }
}

// ---- D: SpMM dual (fp8 gather, full wave per node, 4 B/lane) ----

__global__ __launch_bounds__(256) void spmm_dual_kernel(
    const unsigned char* __restrict__ y12,
    float* __restrict__ o1,        // d_out + 128, stride 384
    ushort* __restrict__ z2,       // bf16, stride 128 (re-read -> cached)
    const int* __restrict__ off, const uint* __restrict__ es, int n) {
  int node = blockIdx.x * 4 + (threadIdx.x >> 6);
  if (node >= n) return;
  int l = threadIdx.x & 63;
  int s = __builtin_amdgcn_readfirstlane(off[node]);
  int e = __builtin_amdgcn_readfirstlane(off[node + 1]);
  float a0 = 0.f, a1 = 0.f, a2 = 0.f, a3 = 0.f;
  int i = s;
  for (; i + 8 <= e; i += 8) {
    uint u[8];
    float w[8];
#pragma unroll
    for (int j = 0; j < 8; ++j) {
      uint ed = es[i + j];
      w[j] = ew_dec(ed);
      u[j] = *(const uint*)(y12 + (size_t)(ed >> 15) * 256 + l * 4);
    }
#pragma unroll
    for (int j = 0; j < 8; ++j) {
      f32x4 p = fp8x4_dec(u[j]);
      a0 += w[j] * p[0]; a1 += w[j] * p[1];
      a2 += w[j] * p[2]; a3 += w[j] * p[3];
    }
  }
  for (; i < e; ++i) {
    uint ed = es[i];
    float w = ew_dec(ed);
    f32x4 p = fp8x4_dec(*(const uint*)(y12 + (size_t)(ed >> 15) * 256 + l * 4));
    a0 += w * p[0]; a1 += w * p[1]; a2 += w * p[2]; a3 += w * p[3];
  }
  if (l < 32) {
    f32x4 v; v[0] = a0; v[1] = a1; v[2] = a2; v[3] = a3;
    __builtin_nontemporal_store(v, (f32x4*)(o1 + (size_t)node * 384 + l * 4));
  } else {
    u32x2 z;
    z.x = (uint)f2bf(a0) | ((uint)f2bf(a1) << 16);
    z.y = (uint)f2bf(a2) | ((uint)f2bf(a3) << 16);
    *(u32x2*)(z2 + (size_t)node * 128 + (l - 32) * 4) = z;
  }
}

// ---- E: SpMM single (bf16 gather, full wave per node, 4 B/lane = 2 ch) ----

__global__ __launch_bounds__(256) void spmm_single_kernel(
    const ushort* __restrict__ z2,
    float* __restrict__ o2,        // d_out + 256, stride 384
    const int* __restrict__ off, const uint* __restrict__ es, int n) {
  int node = blockIdx.x * 4 + (threadIdx.x >> 6);
  if (node >= n) return;
  int l = threadIdx.x & 63;
  int s = __builtin_amdgcn_readfirstlane(off[node]);
  int e = __builtin_amdgcn_readfirstlane(off[node + 1]);
  float a0 = 0.f, a1 = 0.f;
  int i = s;
  for (; i + 8 <= e; i += 8) {
    uint u[8];
    float w[8];
#pragma unroll
    for (int j = 0; j < 8; ++j) {
      uint ed = es[i + j];
      w[j] = ew_dec(ed);
      u[j] = *(const uint*)(z2 + (size_t)(ed >> 15) * 128 + l * 2);
    }
#pragma unroll
    for (int j = 0; j < 8; ++j) {
      a0 += w[j] * bf2f((ushort)u[j]); a1 += w[j] * bf2f((ushort)(u[j] >> 16));
    }
  }
  for (; i < e; ++i) {
    uint ed = es[i];
    float w = ew_dec(ed);
    uint u = *(const uint*)(z2 + (size_t)(ed >> 15) * 128 + l * 2);
    a0 += w * bf2f((ushort)u); a1 += w * bf2f((ushort)(u >> 16));
  }
  f32x2 v; v.x = a0; v.y = a1;
  __builtin_nontemporal_store(v, (f32x2*)(o2 + (size_t)node * 384 + l * 2));
}

// ---------------- launch ----------------

extern "C" void kernel_launch(void* const* d_in, const int* in_sizes, int n_in,
                              void* d_out, int out_size, void* d_ws, size_t ws_size,
                              hipStream_t stream) {
  const float* x   = (const float*)d_in[0];
  const int*   row = (const int*)d_in[1];
  const int*   col = (const int*)d_in[2];
  const float* ew  = (const float*)d_in[3];
  const float* W0  = (const float*)d_in[4];
  const float* b0  = (const float*)d_in[5];
  const float* W1  = (const float*)d_in[6];
  const float* b1  = (const float*)d_in[7];
  const float* W2  = (const float*)d_in[8];
  const float* b2  = (const float*)d_in[9];
  float* out = (float*)d_out;

  int n = in_sizes[0] / 128;
  int E = in_sizes[1];

  char* p = (char*)d_ws;
  size_t o = 0;
  unsigned char* y12 = (unsigned char*)(p + o); o = align256(o + (size_t)n * 256);
  ushort* z2  = (ushort*)(p + o); o = align256(o + (size_t)n * 128 * 2);
  ushort* Wt  = (ushort*)(p + o); o = align256(o + (size_t)3 * 16384 * 2);
  int* bcnt   = (int*)(p + o);    o = align256(o + (size_t)(NBUCK_MAX + 2) * 4);
  int* done   = bcnt + NBUCK_MAX;      // zeroed with bcnt
  int* boff   = (int*)(p + o);    o = align256(o + (size_t)(NBUCK_MAX + 1) * 4);
  int* gcur   = (int*)(p + o);    o = align256(o + (size_t)NBUCK_MAX * 4);
  int* offp   = (int*)(p + o);    o = align256(o + ((size_t)n + 1) * 4);
  int* chist  = (int*)(p + o);    o = align256(o + (size_t)NCHUNK * NBUCK_MAX * 4);
  int2* es_t  = (int2*)(p + o);   o = align256(o + (size_t)E * 8);
  uint* es    = (uint*)(p + o);   o = align256(o + (size_t)E * 4);
  (void)ws_size; (void)n_in; (void)out_size;

  int nbuck = (n + 127) >> 7;
  int ng = (n + 255) / 256;
  int chunk = (E + NCHUNK - 1) / NCHUNK;

  hipMemsetAsync(bcnt, 0, (size_t)(NBUCK_MAX + 2) * 4, stream);

  // A: chunk hist (persisted) + W prep, tail-scan by last block
  build_a_kernel<<<NCHUNK + PREP_BLOCKS, 512, 0, stream>>>(
      row, bcnt, chist, E, chunk, W0, W1, W2, Wt, done, boff, gcur, offp, n);

  // B: binned scatter (no counting pass)
  bin_scatter<<<NCHUNK, 512, 0, stream>>>(row, col, ew, gcur, chist, es_t, E, chunk);

  // C+G: per-bucket node sort (4-B records) + fused 3x GEMM
  sort_gemm_kernel<<<ng + nbuck, 256, 0, stream>>>(
      es_t, boff, es, offp, ng,
      x, Wt, b0, b1, b2, out, y12, n);

  // D: x1 -> out[:,128:256] (NT), z2 (bf16, cached) -> ws
  spmm_dual_kernel<<<(n + 3) / 4, 256, 0, stream>>>(y12, out + 128, z2,
                                                    offp, es, n);
  // E: x2 = A*z2 -> out[:,256:384] (NT)
  spmm_single_kernel<<<(n + 3) / 4, 256, 0, stream>>>(z2, out + 256,
                                                      offp, es, n);
}